// Round 2
// baseline (1038.976 us; speedup 1.0000x reference)
//
#include <hip/hip_runtime.h>

namespace {
constexpr float kL2Reg  = 0.1f;
constexpr float kRho    = 1.0f;
constexpr float kSigma  = 2.0f * kL2Reg + kRho;   // 1.2
constexpr float kJitter = 1e-5f;
constexpr int   kIters  = 100;
constexpr int   MD = 16;     // constraint rows
constexpr int   ND = 32;     // variables
constexpr int   SPB = 16;    // samples per block (4 waves * 4 groups)
constexpr int   AS  = 132;   // A sample stride in float4 (528 floats; 528%32==16 -> 2-way max)
constexpr int   SS  = 36;    // s-buffer stride in floats (36%32==4 -> conflict-free b128 reads)
}

// A tile layout in LDS: per sample, 16 rows x 8 float4, f4 index xor-swizzled with row.
__device__ __forceinline__ float4 lds_a4(const float* As, int r, int j) {
    return *reinterpret_cast<const float4*>(&As[r * 32 + ((j ^ (r & 7)) << 2)]);
}
__device__ __forceinline__ float lds_a(const float* As, int r, int n) {
    return As[r * 32 + ((((n >> 2) ^ (r & 7)) << 2) | (n & 3))];
}

__global__ void __launch_bounds__(256, 4)   // force VGPR<=128 -> 4 waves/SIMD
admm_qp_kernel(const float* __restrict__ Ag, const float* __restrict__ bg,
               const float* __restrict__ cg, const float* __restrict__ lbg,
               const float* __restrict__ ubg, float* __restrict__ outg)
{
    __shared__ float A_lds[SPB * AS * 4];   // 33792 B
    __shared__ float S_lds[SPB * SS];       //  2304 B

    const int t = threadIdx.x;

    // ---- stage A for the block's 16 samples into LDS (coalesced, xor-swizzled f4)
    {
        const float4* src = reinterpret_cast<const float4*>(Ag) +
                            (size_t)blockIdx.x * (SPB * MD * ND / 4);
        float4* dst = reinterpret_cast<float4*>(A_lds);
        #pragma unroll
        for (int r = 0; r < (SPB * MD * ND / 4) / 256; ++r) {   // 8
            int idx = r * 256 + t;
            int smp = idx >> 7;          // 128 f4 per sample
            int row = (idx >> 3) & 15;
            int j   = idx & 7;
            dst[smp * AS + row * 8 + (j ^ (row & 7))] = src[idx];
        }
    }
    __syncthreads();

    const int lane = t & 63;
    const int l    = lane & 15;                     // lane within 16-lane group
    const int smp  = (t >> 6) * 4 + (lane >> 4);    // sample within block
    const size_t gs = (size_t)blockIdx.x * SPB + smp;
    const float* As = &A_lds[smp * AS * 4];
    float* Sb = &S_lds[smp * SS];

    // ---- M = A A^T + jitter*I (row l), augmented identity. Ar dies after this block.
    float Mrow[16], Vrow[16];
    {
        float Ar[32];
        #pragma unroll
        for (int j = 0; j < 8; ++j) {
            float4 v = lds_a4(As, l, j);
            Ar[4*j+0] = v.x; Ar[4*j+1] = v.y; Ar[4*j+2] = v.z; Ar[4*j+3] = v.w;
        }
        #pragma unroll
        for (int k = 0; k < 16; ++k) {
            float acc = 0.f;
            #pragma unroll
            for (int j = 0; j < 8; ++j) {
                float4 v = lds_a4(As, k, j);
                acc += Ar[4*j+0]*v.x + Ar[4*j+1]*v.y + Ar[4*j+2]*v.z + Ar[4*j+3]*v.w;
            }
            Mrow[k] = acc + ((k == l) ? kJitter : 0.f);
            Vrow[k] = (k == l) ? 1.f : 0.f;
        }
    }

    // ---- Gauss-Jordan inverse of M (SPD -> no pivoting). Lane l holds row l of [M|V].
    #pragma unroll
    for (int k = 0; k < 16; ++k) {
        float pk = __shfl(Mrow[k], k, 16);
        float ip = 1.f / pk;
        float f  = (l == k) ? 0.f : Mrow[k] * ip;
        #pragma unroll
        for (int j = k; j < 16; ++j) {
            float mj = __shfl(Mrow[j], k, 16);
            float nm = Mrow[j] - f * mj;
            Mrow[j] = (l == k) ? mj * ip : nm;
        }
        #pragma unroll
        for (int j = 0; j < 16; ++j) {
            float vj = __shfl(Vrow[j], k, 16);
            float nv = Vrow[j] - f * vj;
            Vrow[j] = (l == k) ? vj * ip : nv;
        }
    }

    // ---- w = Minv b (scalar per lane), while Vrow is live
    float w = 0.f;
    {
        float bval = bg[gs * MD + l];
        #pragma unroll
        for (int k = 0; k < 16; ++k) w += Vrow[k] * __shfl(bval, k, 16);
    }

    // ---- C = A^T Minv (rows l, l+16 packed as float2). Vrow dies after this.
    float2 Cc[16];
    #pragma unroll
    for (int m = 0; m < 16; ++m) Cc[m] = make_float2(0.f, 0.f);
    #pragma unroll
    for (int k = 0; k < 16; ++k) {
        float a0 = lds_a(As, k, l);
        float a1 = lds_a(As, k, l + 16);
        #pragma unroll
        for (int m = 0; m < 16; ++m) {
            float mv = __shfl(Vrow[m], k, 16);
            Cc[m].x += a0 * mv;
            Cc[m].y += a1 * mv;
        }
    }

    // ---- P = (I - C A)/sigma, rows l and l+16 packed: Pp[n] = (P[l][n], P[l+16][n]).
    float2 Pp[32];
    #pragma unroll
    for (int n = 0; n < 32; ++n) Pp[n] = make_float2(0.f, 0.f);
    #pragma unroll
    for (int m = 0; m < 16; ++m) {
        float2 cm = Cc[m];
        #pragma unroll
        for (int j = 0; j < 8; ++j) {
            float4 v = lds_a4(As, m, j);
            Pp[4*j+0].x += cm.x*v.x; Pp[4*j+0].y += cm.y*v.x;
            Pp[4*j+1].x += cm.x*v.y; Pp[4*j+1].y += cm.y*v.y;
            Pp[4*j+2].x += cm.x*v.z; Pp[4*j+2].y += cm.y*v.z;
            Pp[4*j+3].x += cm.x*v.w; Pp[4*j+3].y += cm.y*v.w;
        }
    }
    constexpr float inv_sigma = 1.f / kSigma;
    #pragma unroll
    for (int n = 0; n < 32; ++n) {
        Pp[n].x = (((n == l)      ? 1.f : 0.f) - Pp[n].x) * inv_sigma;
        Pp[n].y = (((n == l + 16) ? 1.f : 0.f) - Pp[n].y) * inv_sigma;
    }

    // ---- d = A^T w - P c  (packed float2)
    float2 d2;
    {
        float2 q = make_float2(0.f, 0.f);
        #pragma unroll
        for (int m = 0; m < 16; ++m) {
            float wm = __shfl(w, m, 16);
            q.x += lds_a(As, m, l)      * wm;
            q.y += lds_a(As, m, l + 16) * wm;
        }
        float cv0 = cg[gs * ND + l];
        float cv1 = cg[gs * ND + l + 16];
        d2 = q;
        #pragma unroll
        for (int n = 0; n < 16; ++n) {
            float ca = __shfl(cv0, n, 16);
            float cb = __shfl(cv1, n, 16);
            d2.x -= Pp[n].x * ca + Pp[n + 16].x * cb;
            d2.y -= Pp[n].y * ca + Pp[n + 16].y * cb;
        }
    }

    // ---- ADMM iterations: all state packed float2 (components l and l+16)
    float2 lb2 = make_float2(lbg[gs * ND + l], lbg[gs * ND + l + 16]);
    float2 ub2 = make_float2(ubg[gs * ND + l], ubg[gs * ND + l + 16]);
    float2 z2  = make_float2(fminf(fmaxf(0.f, lb2.x), ub2.x),
                             fminf(fmaxf(0.f, lb2.y), ub2.y));
    float2 u2  = make_float2(0.f, 0.f);
    float2 x2  = make_float2(0.f, 0.f);

    for (int it = 0; it < kIters; ++it) {
        float2 s = make_float2(kRho * (z2.x - u2.x), kRho * (z2.y - u2.y));
        *reinterpret_cast<float2*>(&Sb[l * 2]) = s;   // slot l: (s[l], s[l+16])
        asm volatile("s_waitcnt lgkmcnt(0)" ::: "memory");  // wave-synchronous exchange
        // 4 independent accumulator chains (8 deep each) to cut dependent latency;
        // each pair (x, y) shares its scalar multiplier -> v_pk_fma_f32-shaped.
        float2 a0 = d2;
        float2 a1 = make_float2(0.f, 0.f);
        float2 a2 = make_float2(0.f, 0.f);
        float2 a3 = make_float2(0.f, 0.f);
        #pragma unroll
        for (int k = 0; k < 8; ++k) {
            // (s[2k], s[2k+16], s[2k+1], s[2k+17]) -- uniform per group, conflict-free
            float4 sp = *reinterpret_cast<const float4*>(&Sb[k * 4]);
            a0.x += Pp[2*k].x      * sp.x;  a0.y += Pp[2*k].y      * sp.x;
            a1.x += Pp[2*k+16].x   * sp.y;  a1.y += Pp[2*k+16].y   * sp.y;
            a2.x += Pp[2*k+1].x    * sp.z;  a2.y += Pp[2*k+1].y    * sp.z;
            a3.x += Pp[2*k+17].x   * sp.w;  a3.y += Pp[2*k+17].y   * sp.w;
        }
        x2.x = (a0.x + a1.x) + (a2.x + a3.x);
        x2.y = (a0.y + a1.y) + (a2.y + a3.y);
        float2 t2 = make_float2(x2.x + u2.x, x2.y + u2.y);
        z2.x = fminf(fmaxf(t2.x, lb2.x), ub2.x);
        z2.y = fminf(fmaxf(t2.y, lb2.y), ub2.y);
        u2.x = t2.x - z2.x;
        u2.y = t2.y - z2.y;
    }

    outg[gs * ND + l]      = x2.x;
    outg[gs * ND + l + 16] = x2.y;
}

extern "C" void kernel_launch(void* const* d_in, const int* in_sizes, int n_in,
                              void* d_out, int out_size, void* d_ws, size_t ws_size,
                              hipStream_t stream) {
    const float* A  = (const float*)d_in[0];
    const float* b  = (const float*)d_in[1];
    const float* c  = (const float*)d_in[2];
    const float* lb = (const float*)d_in[3];
    const float* ub = (const float*)d_in[4];
    float* out = (float*)d_out;
    const int B = in_sizes[1] / MD;      // 32768 samples
    const int grid = B / SPB;            // 2048 blocks of 256 threads (16 samples each)
    admm_qp_kernel<<<grid, 256, 0, stream>>>(A, b, c, lb, ub, out);
}